// Round 1
// baseline (3615.513 us; speedup 1.0000x reference)
//
#include <hip/hip_runtime.h>
#include <math.h>

#define EMB 64

__global__ void count_k(const int* __restrict__ el, int* __restrict__ cnt, int n) {
    int i = blockIdx.x * blockDim.x + threadIdx.x;
    if (i < n) atomicAdd(cnt + el[i], 1);
}

__global__ void init_out_k(const float4* __restrict__ src, float4* __restrict__ dst, int n4) {
    int i = blockIdx.x * blockDim.x + threadIdx.x;
    if (i < n4) dst[i] = src[i];
}

// 16 threads per edge; each thread handles 4 contiguous floats (one float4 of noise).
__global__ void scatter_k(const float* __restrict__ noise, const int* __restrict__ el,
                          const int* __restrict__ cnt, float* __restrict__ out,
                          float sigma, int n_edges) {
    long long tid = (long long)blockIdx.x * blockDim.x + threadIdx.x;
    int e = (int)(tid >> 4);
    if (e >= n_edges) return;
    int q = (int)(tid & 15);
    int loc = el[e];
    float s = sigma / (float)cnt[loc];
    const float4 v = *reinterpret_cast<const float4*>(noise + ((long long)e << 6) + (q << 2));
    float* dst = out + ((long long)loc << 6) + (q << 2);
    atomicAdd(dst + 0, v.x * s);
    atomicAdd(dst + 1, v.y * s);
    atomicAdd(dst + 2, v.z * s);
    atomicAdd(dst + 3, v.w * s);
}

extern "C" void kernel_launch(void* const* d_in, const int* in_sizes, int n_in,
                              void* d_out, int out_size, void* d_ws, size_t ws_size,
                              hipStream_t stream) {
    const float* loc_emb = (const float*)d_in[0];
    const float* noise   = (const float*)d_in[1];
    const int*   el      = (const int*)d_in[2];
    float* out = (float*)d_out;

    int n_locs  = in_sizes[0] / EMB;
    int n_edges = in_sizes[2];

    int* cnt = (int*)d_ws;
    hipMemsetAsync(cnt, 0, (size_t)n_locs * sizeof(int), stream);

    // 1) per-location edge counts
    count_k<<<(n_edges + 255) / 256, 256, 0, stream>>>(el, cnt, n_edges);

    // 2) out = loc_emb
    int n4 = n_locs * EMB / 4;
    init_out_k<<<(n4 + 255) / 256, 256, 0, stream>>>(
        (const float4*)loc_emb, (float4*)out, n4);

    // 3) scatter-add scaled noise
    double sigma = 1.0 * sqrt(2.0 * log(1.25 / 1e-5)) / 1.0;
    long long total = (long long)n_edges * 16;
    int blocks = (int)((total + 255) / 256);
    scatter_k<<<blocks, 256, 0, stream>>>(noise, el, cnt, out, (float)sigma, n_edges);
}

// Round 2
// 905.670 us; speedup vs baseline: 3.9921x; 3.9921x over previous
//
#include <hip/hip_runtime.h>
#include <math.h>

#define EMB 64

// ---------- CSR build ----------

__global__ void count_k(const int* __restrict__ el, int* __restrict__ cnt, int n) {
    int i = blockIdx.x * blockDim.x + threadIdx.x;
    if (i < n) atomicAdd(cnt + el[i], 1);
}

__global__ void block_sum_k(const int* __restrict__ cnt, int* __restrict__ part, int n) {
    __shared__ int s[256];
    int i = blockIdx.x * 256 + threadIdx.x;
    s[threadIdx.x] = (i < n) ? cnt[i] : 0;
    __syncthreads();
    for (int off = 128; off > 0; off >>= 1) {
        if (threadIdx.x < off) s[threadIdx.x] += s[threadIdx.x + off];
        __syncthreads();
    }
    if (threadIdx.x == 0) part[blockIdx.x] = s[0];
}

// single-block exclusive scan of nb (<=4096) partials, 1024 threads
__global__ void scan_part_k(int* __restrict__ part, int nb) {
    __shared__ int s[4096];
    for (int i = threadIdx.x; i < 4096; i += 1024) s[i] = (i < nb) ? part[i] : 0;
    __syncthreads();
    for (int off = 1; off < 4096; off <<= 1) {
        int vals[4];
        #pragma unroll
        for (int j = 0; j < 4; ++j) {
            int i = threadIdx.x + j * 1024;
            vals[j] = (i >= off) ? s[i - off] : 0;
        }
        __syncthreads();
        #pragma unroll
        for (int j = 0; j < 4; ++j) {
            int i = threadIdx.x + j * 1024;
            s[i] += vals[j];
        }
        __syncthreads();
    }
    for (int i = threadIdx.x; i < nb; i += 1024) part[i] = (i == 0) ? 0 : s[i - 1];
}

__global__ void scan_block_k(const int* __restrict__ cnt, const int* __restrict__ part,
                             int* __restrict__ offs, int* __restrict__ cursor, int n) {
    __shared__ int s[256];
    int i = blockIdx.x * 256 + threadIdx.x;
    int v = (i < n) ? cnt[i] : 0;
    s[threadIdx.x] = v;
    __syncthreads();
    for (int off = 1; off < 256; off <<= 1) {
        int t = (threadIdx.x >= (unsigned)off) ? s[threadIdx.x - off] : 0;
        __syncthreads();
        s[threadIdx.x] += t;
        __syncthreads();
    }
    if (i < n) {
        int excl = s[threadIdx.x] - v + part[blockIdx.x];
        offs[i] = excl;
        cursor[i] = excl;
    }
}

__global__ void fill_csr_k(const int* __restrict__ el, int* __restrict__ cursor,
                           int* __restrict__ csr, int n) {
    int i = blockIdx.x * blockDim.x + threadIdx.x;
    if (i < n) {
        int loc = el[i];
        int pos = atomicAdd(cursor + loc, 1);
        csr[pos] = i;
    }
}

// ---------- gather: 16 lanes per location, float4 per lane ----------

__global__ void gather_k(const float* __restrict__ loc_emb, const float* __restrict__ noise,
                         const int* __restrict__ cnt, const int* __restrict__ offs,
                         const int* __restrict__ csr, float* __restrict__ out,
                         float sigma, int n_locs) {
    int gid = blockIdx.x * blockDim.x + threadIdx.x;
    int loc = gid >> 4;
    if (loc >= n_locs) return;
    int q = gid & 15;
    int c = cnt[loc];
    int st = offs[loc];
    float4 acc = make_float4(0.f, 0.f, 0.f, 0.f);
    for (int i = 0; i < c; ++i) {
        int e = csr[st + i];
        const float4 v = *reinterpret_cast<const float4*>(noise + ((long long)e << 6) + (q << 2));
        acc.x += v.x; acc.y += v.y; acc.z += v.z; acc.w += v.w;
    }
    float s = (c > 0) ? sigma / (float)c : 0.f;
    const float4 b = *reinterpret_cast<const float4*>(loc_emb + ((long long)loc << 6) + (q << 2));
    float4 o;
    o.x = b.x + s * acc.x;
    o.y = b.y + s * acc.y;
    o.z = b.z + s * acc.z;
    o.w = b.w + s * acc.w;
    *reinterpret_cast<float4*>(out + ((long long)loc << 6) + (q << 2)) = o;
}

extern "C" void kernel_launch(void* const* d_in, const int* in_sizes, int n_in,
                              void* d_out, int out_size, void* d_ws, size_t ws_size,
                              hipStream_t stream) {
    const float* loc_emb = (const float*)d_in[0];
    const float* noise   = (const float*)d_in[1];
    const int*   el      = (const int*)d_in[2];
    float* out = (float*)d_out;

    int n_locs  = in_sizes[0] / EMB;
    int n_edges = in_sizes[2];

    // workspace layout
    char* w = (char*)d_ws;
    int* cnt    = (int*)w;                 w += (size_t)n_locs * sizeof(int);
    int* offs   = (int*)w;                 w += (size_t)n_locs * sizeof(int);
    int* cursor = (int*)w;                 w += (size_t)n_locs * sizeof(int);
    int* part   = (int*)w;                 w += 4096 * sizeof(int);
    int* csr    = (int*)w;

    int nb = (n_locs + 255) / 256;

    hipMemsetAsync(cnt, 0, (size_t)n_locs * sizeof(int), stream);

    count_k<<<(n_edges + 255) / 256, 256, 0, stream>>>(el, cnt, n_edges);
    block_sum_k<<<nb, 256, 0, stream>>>(cnt, part, n_locs);
    scan_part_k<<<1, 1024, 0, stream>>>(part, nb);
    scan_block_k<<<nb, 256, 0, stream>>>(cnt, part, offs, cursor, n_locs);
    fill_csr_k<<<(n_edges + 255) / 256, 256, 0, stream>>>(el, cursor, csr, n_edges);

    double sigma = 1.0 * sqrt(2.0 * log(1.25 / 1e-5)) / 1.0;
    long long total = (long long)n_locs * 16;
    int blocks = (int)((total + 255) / 256);
    gather_k<<<blocks, 256, 0, stream>>>(loc_emb, noise, cnt, offs, csr, out,
                                         (float)sigma, n_locs);
}

// Round 4
// 816.196 us; speedup vs baseline: 4.4297x; 1.1096x over previous
//
#include <hip/hip_runtime.h>
#include <math.h>

#define EMB 64

typedef float f32x4 __attribute__((ext_vector_type(4)));

// ---------- CSR build ----------

__global__ void count_k(const int* __restrict__ el, int* __restrict__ cnt, int n) {
    int i = blockIdx.x * blockDim.x + threadIdx.x;
    if (i < n) atomicAdd(cnt + el[i], 1);
}

__global__ void block_sum_k(const int* __restrict__ cnt, int* __restrict__ part, int n) {
    __shared__ int s[256];
    int i = blockIdx.x * 256 + threadIdx.x;
    s[threadIdx.x] = (i < n) ? cnt[i] : 0;
    __syncthreads();
    for (int off = 128; off > 0; off >>= 1) {
        if (threadIdx.x < off) s[threadIdx.x] += s[threadIdx.x + off];
        __syncthreads();
    }
    if (threadIdx.x == 0) part[blockIdx.x] = s[0];
}

// single-block exclusive scan of nb (<=4096) partials, 1024 threads
__global__ void scan_part_k(int* __restrict__ part, int nb) {
    __shared__ int s[4096];
    for (int i = threadIdx.x; i < 4096; i += 1024) s[i] = (i < nb) ? part[i] : 0;
    __syncthreads();
    for (int off = 1; off < 4096; off <<= 1) {
        int vals[4];
        #pragma unroll
        for (int j = 0; j < 4; ++j) {
            int i = threadIdx.x + j * 1024;
            vals[j] = (i >= off) ? s[i - off] : 0;
        }
        __syncthreads();
        #pragma unroll
        for (int j = 0; j < 4; ++j) {
            int i = threadIdx.x + j * 1024;
            s[i] += vals[j];
        }
        __syncthreads();
    }
    for (int i = threadIdx.x; i < nb; i += 1024) part[i] = (i == 0) ? 0 : s[i - 1];
}

__global__ void scan_block_k(const int* __restrict__ cnt, const int* __restrict__ part,
                             int* __restrict__ offs, int* __restrict__ cursor, int n) {
    __shared__ int s[256];
    int i = blockIdx.x * 256 + threadIdx.x;
    int v = (i < n) ? cnt[i] : 0;
    s[threadIdx.x] = v;
    __syncthreads();
    for (int off = 1; off < 256; off <<= 1) {
        int t = (threadIdx.x >= (unsigned)off) ? s[threadIdx.x - off] : 0;
        __syncthreads();
        s[threadIdx.x] += t;
        __syncthreads();
    }
    if (i < n) {
        int excl = s[threadIdx.x] - v + part[blockIdx.x];
        offs[i] = excl;
        cursor[i] = excl;
    }
}

__global__ void fill_csr_k(const int* __restrict__ el, int* __restrict__ cursor,
                           int* __restrict__ csr, int n) {
    int i = blockIdx.x * blockDim.x + threadIdx.x;
    if (i < n) {
        int loc = el[i];
        int pos = atomicAdd(cursor + loc, 1);
        csr[pos] = i;
    }
}

// ---------- gather: 16 lanes per location, float4 per lane, 4 rows in flight ----------

__device__ __forceinline__ f32x4 ld_row_nt(const float* noise, int e, int q) {
    const f32x4* p = reinterpret_cast<const f32x4*>(noise + ((long long)e << 6)) + q;
    return __builtin_nontemporal_load(p);
}

__global__ void gather_k(const float* __restrict__ loc_emb, const float* __restrict__ noise,
                         const int* __restrict__ cnt, const int* __restrict__ offs,
                         const int* __restrict__ csr, float* __restrict__ out,
                         float sigma, int n_locs) {
    int gid = blockIdx.x * blockDim.x + threadIdx.x;
    int loc = gid >> 4;
    if (loc >= n_locs) return;
    int q = gid & 15;
    int c = cnt[loc];
    int st = offs[loc];
    f32x4 acc = (f32x4)(0.f);
    for (int i = 0; i < c; i += 4) {
        int r = c - i;          // >= 1
        int b0 = st + i;
        int e0 = csr[b0];
        int e1 = csr[b0 + (r > 1 ? 1 : 0)];
        int e2 = csr[b0 + (r > 2 ? 2 : 0)];
        int e3 = csr[b0 + (r > 3 ? 3 : 0)];
        f32x4 v0 = ld_row_nt(noise, e0, q);
        f32x4 v1 = ld_row_nt(noise, e1, q);
        f32x4 v2 = ld_row_nt(noise, e2, q);
        f32x4 v3 = ld_row_nt(noise, e3, q);
        acc += v0;
        if (r > 1) acc += v1;
        if (r > 2) acc += v2;
        if (r > 3) acc += v3;
    }
    float s = (c > 0) ? sigma / (float)c : 0.f;
    const f32x4* bp = reinterpret_cast<const f32x4*>(loc_emb + ((long long)loc << 6)) + q;
    f32x4 b = __builtin_nontemporal_load(bp);
    f32x4 o = b + s * acc;
    f32x4* op = reinterpret_cast<f32x4*>(out + ((long long)loc << 6)) + q;
    __builtin_nontemporal_store(o, op);
}

extern "C" void kernel_launch(void* const* d_in, const int* in_sizes, int n_in,
                              void* d_out, int out_size, void* d_ws, size_t ws_size,
                              hipStream_t stream) {
    const float* loc_emb = (const float*)d_in[0];
    const float* noise   = (const float*)d_in[1];
    const int*   el      = (const int*)d_in[2];
    float* out = (float*)d_out;

    int n_locs  = in_sizes[0] / EMB;
    int n_edges = in_sizes[2];

    // workspace layout
    char* w = (char*)d_ws;
    int* cnt    = (int*)w;                 w += (size_t)n_locs * sizeof(int);
    int* offs   = (int*)w;                 w += (size_t)n_locs * sizeof(int);
    int* cursor = (int*)w;                 w += (size_t)n_locs * sizeof(int);
    int* part   = (int*)w;                 w += 4096 * sizeof(int);
    int* csr    = (int*)w;

    int nb = (n_locs + 255) / 256;

    (void)hipMemsetAsync(cnt, 0, (size_t)n_locs * sizeof(int), stream);

    count_k<<<(n_edges + 255) / 256, 256, 0, stream>>>(el, cnt, n_edges);
    block_sum_k<<<nb, 256, 0, stream>>>(cnt, part, n_locs);
    scan_part_k<<<1, 1024, 0, stream>>>(part, nb);
    scan_block_k<<<nb, 256, 0, stream>>>(cnt, part, offs, cursor, n_locs);
    fill_csr_k<<<(n_edges + 255) / 256, 256, 0, stream>>>(el, cursor, csr, n_edges);

    double sigma = 1.0 * sqrt(2.0 * log(1.25 / 1e-5)) / 1.0;
    long long total = (long long)n_locs * 16;
    int blocks = (int)((total + 255) / 256);
    gather_k<<<blocks, 256, 0, stream>>>(loc_emb, noise, cnt, offs, csr, out,
                                         (float)sigma, n_locs);
}

// Round 5
// 541.915 us; speedup vs baseline: 6.6717x; 1.5061x over previous
//
#include <hip/hip_runtime.h>
#include <math.h>

#define EMB 64

typedef float f32x4 __attribute__((ext_vector_type(4)));

// ---------- CSR build ----------

// one pass: count AND per-edge rank (rank = atomicAdd return)
__global__ void count_rank_k(const int* __restrict__ el, int* __restrict__ cnt,
                             int* __restrict__ rank, int n) {
    int i = blockIdx.x * blockDim.x + threadIdx.x;
    if (i < n) rank[i] = atomicAdd(cnt + el[i], 1);
}

__global__ void block_sum_k(const int* __restrict__ cnt, int* __restrict__ part, int n) {
    __shared__ int s[256];
    int i = blockIdx.x * 256 + threadIdx.x;
    s[threadIdx.x] = (i < n) ? cnt[i] : 0;
    __syncthreads();
    for (int off = 128; off > 0; off >>= 1) {
        if (threadIdx.x < off) s[threadIdx.x] += s[threadIdx.x + off];
        __syncthreads();
    }
    if (threadIdx.x == 0) part[blockIdx.x] = s[0];
}

// single-block exclusive scan of nb (<=4096) partials, 1024 threads
__global__ void scan_part_k(int* __restrict__ part, int nb) {
    __shared__ int s[4096];
    for (int i = threadIdx.x; i < 4096; i += 1024) s[i] = (i < nb) ? part[i] : 0;
    __syncthreads();
    for (int off = 1; off < 4096; off <<= 1) {
        int vals[4];
        #pragma unroll
        for (int j = 0; j < 4; ++j) {
            int i = threadIdx.x + j * 1024;
            vals[j] = (i >= off) ? s[i - off] : 0;
        }
        __syncthreads();
        #pragma unroll
        for (int j = 0; j < 4; ++j) {
            int i = threadIdx.x + j * 1024;
            s[i] += vals[j];
        }
        __syncthreads();
    }
    for (int i = threadIdx.x; i < nb; i += 1024) part[i] = (i == 0) ? 0 : s[i - 1];
}

__global__ void scan_block_k(const int* __restrict__ cnt, const int* __restrict__ part,
                             int* __restrict__ offs, int n) {
    __shared__ int s[256];
    int i = blockIdx.x * 256 + threadIdx.x;
    int v = (i < n) ? cnt[i] : 0;
    s[threadIdx.x] = v;
    __syncthreads();
    for (int off = 1; off < 256; off <<= 1) {
        int t = (threadIdx.x >= (unsigned)off) ? s[threadIdx.x - off] : 0;
        __syncthreads();
        s[threadIdx.x] += t;
        __syncthreads();
    }
    if (i < n) offs[i] = s[threadIdx.x] - v + part[blockIdx.x];
}

// atomic-free fill using precomputed ranks
__global__ void fill_csr_k(const int* __restrict__ el, const int* __restrict__ rank,
                           const int* __restrict__ offs, int* __restrict__ csr, int n) {
    int i = blockIdx.x * blockDim.x + threadIdx.x;
    if (i < n) csr[offs[el[i]] + rank[i]] = i;
}

// ---------- gather: 16 lanes per location, float4 per lane, 8 rows in flight ----------

__device__ __forceinline__ f32x4 ld_row(const float* noise, int e, int q) {
    // plain (cached) load: duplicate tail loads hit L1, no extra DRAM traffic
    return *(reinterpret_cast<const f32x4*>(noise + ((long long)e << 6)) + q);
}

__global__ void gather_k(const float* __restrict__ loc_emb, const float* __restrict__ noise,
                         const int* __restrict__ cnt, const int* __restrict__ offs,
                         const int* __restrict__ csr, float* __restrict__ out,
                         float sigma, int n_locs) {
    int gid = blockIdx.x * blockDim.x + threadIdx.x;
    int loc = gid >> 4;
    if (loc >= n_locs) return;
    int q = gid & 15;
    int c = cnt[loc];
    int st = offs[loc];
    f32x4 acc = (f32x4)(0.f);
    for (int i = 0; i < c; i += 8) {
        int r = c - i;          // >= 1
        int b0 = st + i;
        int e[8];
        #pragma unroll
        for (int j = 0; j < 8; ++j)
            e[j] = csr[b0 + (j < r ? j : r - 1)];   // clamped, in-bounds
        f32x4 v[8];
        #pragma unroll
        for (int j = 0; j < 8; ++j)
            v[j] = ld_row(noise, e[j], q);          // 8 independent 256B rows in flight
        #pragma unroll
        for (int j = 0; j < 8; ++j)
            if (j < r) acc += v[j];
    }
    float s = (c > 0) ? sigma / (float)c : 0.f;
    const f32x4* bp = reinterpret_cast<const f32x4*>(loc_emb + ((long long)loc << 6)) + q;
    f32x4 b = __builtin_nontemporal_load(bp);
    f32x4 o = b + s * acc;
    f32x4* op = reinterpret_cast<f32x4*>(out + ((long long)loc << 6)) + q;
    __builtin_nontemporal_store(o, op);
}

extern "C" void kernel_launch(void* const* d_in, const int* in_sizes, int n_in,
                              void* d_out, int out_size, void* d_ws, size_t ws_size,
                              hipStream_t stream) {
    const float* loc_emb = (const float*)d_in[0];
    const float* noise   = (const float*)d_in[1];
    const int*   el      = (const int*)d_in[2];
    float* out = (float*)d_out;

    int n_locs  = in_sizes[0] / EMB;
    int n_edges = in_sizes[2];

    // workspace layout
    char* w = (char*)d_ws;
    int* cnt  = (int*)w;                 w += (size_t)n_locs * sizeof(int);
    int* offs = (int*)w;                 w += (size_t)n_locs * sizeof(int);
    int* part = (int*)w;                 w += 4096 * sizeof(int);
    int* rank = (int*)w;                 w += (size_t)n_edges * sizeof(int);
    int* csr  = (int*)w;

    int nb = (n_locs + 255) / 256;

    (void)hipMemsetAsync(cnt, 0, (size_t)n_locs * sizeof(int), stream);

    count_rank_k<<<(n_edges + 255) / 256, 256, 0, stream>>>(el, cnt, rank, n_edges);
    block_sum_k<<<nb, 256, 0, stream>>>(cnt, part, n_locs);
    scan_part_k<<<1, 1024, 0, stream>>>(part, nb);
    scan_block_k<<<nb, 256, 0, stream>>>(cnt, part, offs, n_locs);
    fill_csr_k<<<(n_edges + 255) / 256, 256, 0, stream>>>(el, rank, offs, csr, n_edges);

    double sigma = 1.0 * sqrt(2.0 * log(1.25 / 1e-5)) / 1.0;
    long long total = (long long)n_locs * 16;
    int blocks = (int)((total + 255) / 256);
    gather_k<<<blocks, 256, 0, stream>>>(loc_emb, noise, cnt, offs, csr, out,
                                         (float)sigma, n_locs);
}